// Round 1
// baseline (8372.023 us; speedup 1.0000x reference)
//
#include <hip/hip_runtime.h>
#include <math.h>

// Problem constants (fixed by setup_inputs)
#define TT 64
#define BB 16
#define SS 128
#define DD 512
#define NBLK 144
#define NTH 256
#define BD (BB*DD)               // 8192
#define OUT_HR   (TT*BD)         // 524288
#define OUT_CR   (OUT_HR + BD)
#define OUT_HW   (OUT_CR + BD)
#define OUT_CW   (OUT_HW + BD)
#define OUT_MF   (OUT_CW + BD)   // 557056
#define MAGIC 0x13579BDFu

__device__ __forceinline__ float sigf(float x) { return 1.f / (1.f + __expf(-x)); }

// ---- device-scope grid barrier (persistent kernel, all blocks co-resident) ----
__device__ __forceinline__ void gbar(unsigned* cnt, unsigned& ep) {
  __syncthreads();
  if (threadIdx.x == 0) {
    unsigned target = (++ep) * (unsigned)NBLK;
    __threadfence();  // agent-scope release of prior global writes
    __hip_atomic_fetch_add(cnt, 1u, __ATOMIC_RELEASE, __HIP_MEMORY_SCOPE_AGENT);
    while (__hip_atomic_load(cnt, __ATOMIC_ACQUIRE, __HIP_MEMORY_SCOPE_AGENT) < target)
      __builtin_amdgcn_s_sleep(1);
    __threadfence();  // belt+braces: invalidate before post-barrier reads
  }
  __syncthreads();
}

__device__ __forceinline__ float dot512(const float4* __restrict__ a,
                                        const float4* __restrict__ w) {
  float4 s = make_float4(0.f, 0.f, 0.f, 0.f);
#pragma unroll 8
  for (int k = 0; k < DD/4; ++k) {
    float4 x = a[k], y = w[k];
    s.x = fmaf(x.x, y.x, s.x); s.y = fmaf(x.y, y.y, s.y);
    s.z = fmaf(x.z, y.z, s.z); s.w = fmaf(x.w, y.w, s.w);
  }
  return s.x + s.y + s.z + s.w;
}

// Read-LSTM step ii: hr[ii+1] = cell(emb[ii]@Wih_r^T + hr[ii]@Whh_r^T + b, cr)
// Block r owns hidden dims [4r,4r+4) and their 4 gate columns. 256 outputs, 1/thread.
__device__ __forceinline__ void readLstm(
    int ii, int rR, int tid,
    const float* __restrict__ emb, const float* __restrict__ hrprev,
    const float* __restrict__ Wih_r, const float* __restrict__ Whh_r,
    const float* __restrict__ bih_r, const float* __restrict__ bhh_r,
    float* __restrict__ hrb, float* __restrict__ out, float& cr_reg, float* lds)
{
  const int b = tid & 15, j = tid >> 4;
  const int q = j >> 2, dl = j & 3;
  const int col = (q << 9) + rR*4 + dl;
  float g = dot512((const float4*)(emb + (ii*BB + b)*DD), (const float4*)(Wih_r + col*DD))
          + dot512((const float4*)(hrprev + b*DD),        (const float4*)(Whh_r + col*DD))
          + bih_r[col] + bhh_r[col];
  lds[b*16 + j] = g;
  __syncthreads();
  if (tid < 64) {
    const int b2 = tid & 15, dl2 = tid >> 4;
    const float* gr = lds + b2*16;
    float gi = gr[dl2], gf = gr[4+dl2], gc = gr[8+dl2], go = gr[12+dl2];
    cr_reg = sigf(gf)*cr_reg + sigf(gi)*tanhf(gc);
    float h = sigf(go)*tanhf(cr_reg);
    const int d2 = rR*4 + dl2;
    hrb[((ii+1)&1)*BD + b2*DD + d2] = h;
    if (ii + 1 == TT) { out[OUT_HR + b2*DD + d2] = h; out[OUT_CR + b2*DD + d2] = cr_reg; }
  }
  __syncthreads();
}

// Attention for step i (block = batch b): sim=hr.M, softmax -> zbuf, m -> mbuf
// Mws layout is [b][d][s] (transposed) so everything is s-contiguous.
__device__ __forceinline__ void attn(
    int i, int b, int tid,
    const float* __restrict__ hrb, const float* __restrict__ Mws,
    float* __restrict__ zbuf, float* __restrict__ mbuf, float* lds)
{
  const float* hrp = hrb + ((i+1)&1)*BD + b*DD;
  const float* Mb  = Mws + b*DD*SS;
  {
    const int s4 = (tid & 31) * 4, dh = tid >> 5;  // 8 d-chunks of 64
    float4 a = make_float4(0,0,0,0);
    const float* base = Mb + (dh*64)*SS + s4;
#pragma unroll 4
    for (int dd = 0; dd < 64; ++dd) {
      float hv = hrp[dh*64 + dd];
      float4 mm = *(const float4*)(base + dd*SS);
      a.x = fmaf(hv, mm.x, a.x); a.y = fmaf(hv, mm.y, a.y);
      a.z = fmaf(hv, mm.z, a.z); a.w = fmaf(hv, mm.w, a.w);
    }
    *(float4*)(lds + dh*SS + s4) = a;
  }
  __syncthreads();
  float v = 0.f, e = 0.f;
  if (tid < 128) {
#pragma unroll
    for (int h = 0; h < 8; ++h) v += lds[h*SS + tid];
    float wm = v;
    for (int off = 32; off > 0; off >>= 1) wm = fmaxf(wm, __shfl_xor(wm, off));
    if ((tid & 63) == 0) lds[tid >> 6] = wm;
  }
  __syncthreads();
  const float gmax = fmaxf(lds[0], lds[1]);
  if (tid < 128) {
    e = __expf(v - gmax);
    float sm = e;
    for (int off = 32; off > 0; off >>= 1) sm += __shfl_xor(sm, off);
    if ((tid & 63) == 0) lds[2 + (tid >> 6)] = sm;
  }
  __syncthreads();
  const float gsum = lds[2] + lds[3];
  if (tid < 128) {
    float zv = e / gsum;
    zbuf[b*SS + tid] = zv;
    lds[4 + tid] = zv;
  }
  __syncthreads();
#pragma unroll
  for (int rep = 0; rep < 2; ++rep) {
    const int d = tid + rep*256;
    const float4* Mrow = (const float4*)(Mb + d*SS);
    const float4* z4 = (const float4*)(lds + 4);
    float4 a = make_float4(0,0,0,0);
#pragma unroll 8
    for (int k = 0; k < SS/4; ++k) {
      float4 mm = Mrow[k], zz = z4[k];
      a.x = fmaf(mm.x, zz.x, a.x); a.y = fmaf(mm.y, zz.y, a.y);
      a.z = fmaf(mm.z, zz.z, a.z); a.w = fmaf(mm.w, zz.w, a.w);
    }
    mbuf[b*DD + d] = a.x+a.y+a.z+a.w;
  }
  __syncthreads();
}

// comp[b,c] = [hr,m] @ Wc[c,:] + bc[c]; block cb owns cols [4cb,4cb+4); 4 K-chunks/thread
__device__ __forceinline__ void compPhase(
    int i, int cb, int tid,
    const float* __restrict__ hrb, const float* __restrict__ mbuf,
    const float* __restrict__ Wc, const float* __restrict__ bc,
    float* __restrict__ compbuf, float* lds)
{
  const int o = tid >> 2, kq = tid & 3;
  const int b = o & 15, cl = o >> 4;
  const int c = cb*4 + cl;
  const float* src = (kq < 2) ? (hrb + ((i+1)&1)*BD + b*DD + kq*256)
                              : (mbuf + b*DD + (kq-2)*256);
  const float4* s4 = (const float4*)src;
  const float4* w4 = (const float4*)(Wc + c*(2*DD) + kq*256);
  float4 a = make_float4(0,0,0,0);
#pragma unroll 8
  for (int k = 0; k < 64; ++k) {
    float4 x = s4[k], y = w4[k];
    a.x = fmaf(x.x,y.x,a.x); a.y = fmaf(x.y,y.y,a.y);
    a.z = fmaf(x.z,y.z,a.z); a.w = fmaf(x.w,y.w,a.w);
  }
  lds[tid] = a.x+a.y+a.z+a.w;
  __syncthreads();
  if (tid < 64) {
    const int b2 = tid & 15, cl2 = tid >> 4;
    const int c2 = cb*4 + cl2;
    compbuf[b2*DD + c2] = lds[tid*4] + lds[tid*4+1] + lds[tid*4+2] + lds[tid*4+3] + bc[c2];
  }
  __syncthreads();
}

// Write-LSTM step i + fused M update + outputs. Block rB owns hidden dims [4rB,4rB+4).
__device__ __forceinline__ void writeLstm(
    int i, int rB, int tid,
    const float* __restrict__ compbuf, const float* __restrict__ hwprev,
    const float* __restrict__ Wih_w, const float* __restrict__ Whh_w,
    const float* __restrict__ bih_w, const float* __restrict__ bhh_w,
    const float* __restrict__ zbuf,
    float* __restrict__ hwb, float* __restrict__ Mws, float* __restrict__ out,
    float& cw_reg, float* lds)
{
  const int b = tid & 15, j = tid >> 4;
  const int q = j >> 2, dl = j & 3;
  const int col = (q << 9) + rB*4 + dl;
  float g = dot512((const float4*)(compbuf + b*DD), (const float4*)(Wih_w + col*DD))
          + dot512((const float4*)(hwprev + b*DD),  (const float4*)(Whh_w + col*DD))
          + bih_w[col] + bhh_w[col];
  lds[b*16 + j] = g;
  __syncthreads();
  if (tid < 64) {
    const int b2 = tid & 15, dl2 = tid >> 4;
    const float* gr = lds + b2*16;
    float gi = gr[dl2], gf = gr[4+dl2], gc = gr[8+dl2], go = gr[12+dl2];
    cw_reg = sigf(gf)*cw_reg + sigf(gi)*tanhf(gc);
    float h = sigf(go)*tanhf(cw_reg);
    const int d2 = rB*4 + dl2;
    hwb[((i+1)&1)*BD + b2*DD + d2] = h;
    out[i*BD + b2*DD + d2] = h;                     // outputs[t] = hw[t+1]
    if (i == TT-1) { out[OUT_HW + b2*DD + d2] = h; out[OUT_CW + b2*DD + d2] = cw_reg; }
    lds[256 + b2*4 + dl2] = h;
  }
  __syncthreads();
  const bool last = (i == TT-1);
  for (int idx = tid; idx < BB*4*SS; idx += NTH) {
    const int s = idx & 127, row = idx >> 7;
    const int b3 = row >> 2, dl3 = row & 3;
    const float hv = lds[256 + b3*4 + dl3];
    const float zv = zbuf[b3*SS + s];
    float* Mp = Mws + (b3*DD + rB*4 + dl3)*SS + s;
    const float nv = (1.f - zv) * (*Mp + hv);
    *Mp = nv;
    if (last) out[OUT_MF + (b3*SS + s)*DD + rB*4 + dl3] = nv;
  }
  __syncthreads();
}

__global__ void __launch_bounds__(NTH) memnet(
    const float* __restrict__ emb, const float* __restrict__ M_in,
    const float* __restrict__ hr0, const float* __restrict__ cr0,
    const float* __restrict__ hw0, const float* __restrict__ cw0,
    const float* __restrict__ Wih_r, const float* __restrict__ Whh_r,
    const float* __restrict__ bih_r, const float* __restrict__ bhh_r,
    const float* __restrict__ Wih_w, const float* __restrict__ Whh_w,
    const float* __restrict__ bih_w, const float* __restrict__ bhh_w,
    const float* __restrict__ Wc, const float* __restrict__ bc,
    float* __restrict__ out,
    unsigned* flagp, unsigned* cntp,
    float* __restrict__ Mws, float* __restrict__ hrb, float* __restrict__ hwb,
    float* __restrict__ zbuf, float* __restrict__ mbuf, float* __restrict__ compbuf)
{
  const int tid = threadIdx.x;
  const int bid = blockIdx.x;
  __shared__ float lds[1280];

  // ---- init handshake (ws is poisoned 0xAA each launch; block 0 zeroes counter) ----
  if (bid == 0) {
    if (tid == 0) {
      __hip_atomic_store(cntp, 0u, __ATOMIC_RELAXED, __HIP_MEMORY_SCOPE_AGENT);
      __threadfence();
      __hip_atomic_store(flagp, MAGIC, __ATOMIC_RELEASE, __HIP_MEMORY_SCOPE_AGENT);
    }
  } else if (tid == 0) {
    while (__hip_atomic_load(flagp, __ATOMIC_ACQUIRE, __HIP_MEMORY_SCOPE_AGENT) != MAGIC)
      __builtin_amdgcn_s_sleep(1);
  }
  __syncthreads();
  unsigned epoch = 0;

  const bool isZ = bid < BB;        // 16 attention blocks (block = batch)
  const int  rR  = bid - BB;        // read-LSTM blocks 16..143 -> r = 0..127
  const bool isB = bid < 128;       // comp / write-LSTM blocks

  // persistent cell states in registers (tid<64: b=tid&15, dl=tid>>4)
  float cr_reg = 0.f, cw_reg = 0.f;
  if (tid < 64) {
    const int b = tid & 15, dl = tid >> 4;
    if (!isZ) cr_reg = cr0[b*DD + rR*4 + dl];
    if (isB)  cw_reg = cw0[b*DD + bid*4 + dl];
  }

  // ---- prologue: hr[1] (R blocks, reads hr0 directly) + transpose M into ws ----
  if (!isZ)
    readLstm(0, rR, tid, emb, hr0, Wih_r, Whh_r, bih_r, bhh_r, hrb, out, cr_reg, lds);
  for (int e = bid*NTH + tid; e < BB*SS*DD; e += NBLK*NTH) {
    const int b = e >> 16, rem = e & 65535, s = rem >> 9, d = rem & 511;
    Mws[(b*DD + d)*SS + s] = M_in[e];
  }
  gbar(cntp, epoch);

  // ---- main loop: 3 barriers/step, read-LSTM(t+1) pipelined with attention(t) ----
  for (int i = 0; i < TT; ++i) {
    if (isZ) {
      attn(i, bid, tid, hrb, Mws, zbuf, mbuf, lds);
    } else if (i + 1 < TT) {
      readLstm(i+1, rR, tid, emb, hrb + ((i+1)&1)*BD,
               Wih_r, Whh_r, bih_r, bhh_r, hrb, out, cr_reg, lds);
    }
    gbar(cntp, epoch);
    if (isB) compPhase(i, bid, tid, hrb, mbuf, Wc, bc, compbuf, lds);
    gbar(cntp, epoch);
    if (isB) writeLstm(i, bid, tid, compbuf, (i == 0) ? hw0 : (hwb + (i&1)*BD),
                       Wih_w, Whh_w, bih_w, bhh_w, zbuf, hwb, Mws, out, cw_reg, lds);
    gbar(cntp, epoch);
  }
}

extern "C" void kernel_launch(void* const* d_in, const int* in_sizes, int n_in,
                              void* d_out, int out_size, void* d_ws, size_t ws_size,
                              hipStream_t stream) {
  (void)in_sizes; (void)n_in; (void)out_size; (void)ws_size;
  const float* emb   = (const float*)d_in[0];
  const float* M_in  = (const float*)d_in[1];
  const float* hr0   = (const float*)d_in[2];
  const float* cr0   = (const float*)d_in[3];
  const float* hw0   = (const float*)d_in[4];
  const float* cw0   = (const float*)d_in[5];
  const float* Wih_r = (const float*)d_in[6];
  const float* Whh_r = (const float*)d_in[7];
  const float* bih_r = (const float*)d_in[8];
  const float* bhh_r = (const float*)d_in[9];
  const float* Wih_w = (const float*)d_in[10];
  const float* Whh_w = (const float*)d_in[11];
  const float* bih_w = (const float*)d_in[12];
  const float* bhh_w = (const float*)d_in[13];
  const float* Wc    = (const float*)d_in[14];
  const float* bc    = (const float*)d_in[15];
  float* out = (float*)d_out;

  char* wsb = (char*)d_ws;
  unsigned* flagp = (unsigned*)wsb;          // byte 0
  unsigned* cntp  = (unsigned*)(wsb + 256);  // separate cacheline
  float* wsf  = (float*)(wsb + 1024);
  float* Mws  = wsf;                   // B*D*S = 1048576 floats (transposed M)
  float* hrb  = Mws + BB*DD*SS;        // 2*B*D
  float* hwb  = hrb + 2*BD;            // 2*B*D
  float* zbuf = hwb + 2*BD;            // B*S
  float* mbuf = zbuf + BB*SS;          // B*D
  float* compbuf = mbuf + BD;          // B*D   (total ~4.4 MB)

  hipLaunchKernelGGL(memnet, dim3(NBLK), dim3(NTH), 0, stream,
                     emb, M_in, hr0, cr0, hw0, cw0,
                     Wih_r, Whh_r, bih_r, bhh_r,
                     Wih_w, Whh_w, bih_w, bhh_w, Wc, bc,
                     out, flagp, cntp, Mws, hrb, hwb, zbuf, mbuf, compbuf);
}

// Round 2
// 3921.531 us; speedup vs baseline: 2.1349x; 2.1349x over previous
//
#include <hip/hip_runtime.h>
#include <math.h>

// Problem constants (fixed by setup_inputs)
#define TT 64
#define BB 16
#define SS 128
#define DD 512
#define NBLK 256
#define NTH 256
#define BD (BB*DD)               // 8192
#define OUT_HR   (TT*BD)         // 524288
#define OUT_CR   (OUT_HR + BD)
#define OUT_HW   (OUT_CR + BD)
#define OUT_CW   (OUT_HW + BD)
#define OUT_MF   (OUT_CW + BD)   // 557056
#define MAGIC 0x13579BDFu

// workspace float offsets (after 1024-byte header)
#define WF_OFF   0            // Wfused [2048][1024]            = 2,097,152
#define MW_OFF   2097152      // M transposed [16][512][128]    = 1,048,576
#define HRR_OFF  3145728      // hr ring [65][16][512]          =   532,480
#define HWR_OFF  3678208      // hw ring [65][16][512]          =   532,480
#define MR_OFF   4210688      // m ring  [64][16][512]          =   524,288
#define SP_OFF   4734976      // sim partials [16][16][128]     =    32,768

__device__ __forceinline__ float sigf(float x) { return 1.f / (1.f + __expf(-x)); }

// agent-scope (sc1, cache-bypassing) store/load for cross-block data
__device__ __forceinline__ void stg(float* p, float v) {
  __hip_atomic_store(p, v, __ATOMIC_RELAXED, __HIP_MEMORY_SCOPE_AGENT);
}
__device__ __forceinline__ float ldga(const float* p) {
  return __hip_atomic_load(p, __ATOMIC_RELAXED, __HIP_MEMORY_SCOPE_AGENT);
}

// light grid barrier: NO buffer_wbl2 / buffer_inv. All cross-block data is
// written via sc1 stores (write-through to coherence point); __syncthreads
// drains each wave's vmcnt, then one relaxed RMW + relaxed spin.
__device__ __forceinline__ void lbar(unsigned* cnt, unsigned& ep) {
  __syncthreads();
  if (threadIdx.x == 0) {
    unsigned target = (++ep) * (unsigned)NBLK;
    asm volatile("s_waitcnt vmcnt(0)" ::: "memory");
    __hip_atomic_fetch_add(cnt, 1u, __ATOMIC_RELAXED, __HIP_MEMORY_SCOPE_AGENT);
    while (__hip_atomic_load(cnt, __ATOMIC_RELAXED, __HIP_MEMORY_SCOPE_AGENT) < target) {}
  }
  __syncthreads();
}

__device__ __forceinline__ float dotf4(const float* __restrict__ a,
                                       const float* __restrict__ b, int n4) {
  const float4* a4 = (const float4*)a;
  const float4* b4 = (const float4*)b;
  float4 s = make_float4(0.f, 0.f, 0.f, 0.f);
#pragma unroll 8
  for (int k = 0; k < n4; ++k) {
    float4 x = a4[k], y = b4[k];
    s.x = fmaf(x.x, y.x, s.x); s.y = fmaf(x.y, y.y, s.y);
    s.z = fmaf(x.z, y.z, s.z); s.w = fmaf(x.w, y.w, s.w);
  }
  return (s.x + s.y) + (s.z + s.w);
}

__global__ void __launch_bounds__(NTH) memnet(
    const float* __restrict__ emb, const float* __restrict__ M_in,
    const float* __restrict__ hr0, const float* __restrict__ cr0,
    const float* __restrict__ hw0, const float* __restrict__ cw0,
    const float* __restrict__ Wih_r, const float* __restrict__ Whh_r,
    const float* __restrict__ bih_r, const float* __restrict__ bhh_r,
    const float* __restrict__ Wih_w, const float* __restrict__ Whh_w,
    const float* __restrict__ bih_w, const float* __restrict__ bhh_w,
    const float* __restrict__ Wc, const float* __restrict__ bc,
    float* __restrict__ out,
    unsigned* flagp, unsigned* cntp, float* __restrict__ wsf)
{
  const int tid = threadIdx.x;
  const int bid = blockIdx.x;

  // roles (every block has all three):
  const int mb  = bid & 15;          // M-slice batch
  const int mdh = bid >> 4;          // M-slice d-chunk: d in [mdh*32, mdh*32+32)
  const int dr0 = 2 * bid;           // read-LSTM / write-LSTM hidden dims {dr0, dr0+1}

  float* WF  = wsf + WF_OFF;
  float* Mws = wsf + MW_OFF;
  float* hrr = wsf + HRR_OFF;
  float* hwr = wsf + HWR_OFF;
  float* mr  = wsf + MR_OFF;
  float* sp  = wsf + SP_OFF;

  __shared__ float z_lds[SS];        // persistent z_i for own mb
  __shared__ float scr[4352];        // A: sim partials [32][132]; B/C scratch; [4224..] scalars
  __shared__ float gsave[256];       // A: rl partials; B->C: g_hr partials
  __shared__ float bfl[8];           // fused write bias for own 8 cols
  __shared__ float wih_lds[8 * DD];  // prologue: Wih_w rows for own 8 cols

  // ---- init handshake (ws poisoned 0xAA each launch; block 0 zeroes counter) ----
  if (bid == 0) {
    if (tid == 0) {
      __hip_atomic_store(cntp, 0u, __ATOMIC_RELAXED, __HIP_MEMORY_SCOPE_AGENT);
      asm volatile("s_waitcnt vmcnt(0)" ::: "memory");
      __hip_atomic_store(flagp, MAGIC, __ATOMIC_RELAXED, __HIP_MEMORY_SCOPE_AGENT);
    }
  } else if (tid == 0) {
    while (__hip_atomic_load(flagp, __ATOMIC_RELAXED, __HIP_MEMORY_SCOPE_AGENT) != MAGIC) {}
  }
  __syncthreads();
  unsigned ep = 0;

  // persistent cell states on threads [128,160): t=tid-128 -> (b=t&15, dl=t>>4)
  float cr = 0.f, cw = 0.f;
  if (tid >= 128 && tid < 160) {
    const int t = tid - 128, b = t & 15, dl = t >> 4;
    cr = cr0[b * DD + dr0 + dl];
    cw = cw0[b * DD + dr0 + dl];
  }

  // =========================== PROLOGUE ===========================
  // stage Wih_w rows for own 8 write-cols into LDS
  {
    const float2* src;
#pragma unroll
    for (int c = 0; c < 8; ++c) {
      const int col = (c >> 1) * DD + dr0 + (c & 1);
      src = (const float2*)(Wih_w + col * DD);
      ((float2*)(wih_lds + c * DD))[tid] = src[tid];
    }
  }
  __syncthreads();

  // Wfused[col][k] = sum_c Wih_w[col][c] * Wc[c][k]  (own 8 cols; self-owned -> normal stores)
  {
    float4 acc[8];
#pragma unroll
    for (int c = 0; c < 8; ++c) acc[c] = make_float4(0.f, 0.f, 0.f, 0.f);
    const int k0 = tid * 4;
    for (int cc = 0; cc < DD; ++cc) {
      float4 wc4 = *(const float4*)(Wc + cc * 1024 + k0);
#pragma unroll
      for (int c = 0; c < 8; ++c) {
        const float wv = wih_lds[c * DD + cc];
        acc[c].x = fmaf(wv, wc4.x, acc[c].x);
        acc[c].y = fmaf(wv, wc4.y, acc[c].y);
        acc[c].z = fmaf(wv, wc4.z, acc[c].z);
        acc[c].w = fmaf(wv, wc4.w, acc[c].w);
      }
    }
#pragma unroll
    for (int c = 0; c < 8; ++c) {
      const int col = (c >> 1) * DD + dr0 + (c & 1);
      *(float4*)(WF + col * 1024 + k0) = acc[c];
    }
  }
  // bfused[c] = bih_w + bhh_w + Wih_w[col,:]·bc
  if (tid < 8) {
    const int col = (tid >> 1) * DD + dr0 + (tid & 1);
    float s = 0.f;
    for (int cc = 0; cc < DD; ++cc) s = fmaf(wih_lds[tid * DD + cc], bc[cc], s);
    bfl[tid] = s + bih_w[col] + bhh_w[col];
  }

  // transpose own M slice: Mws[mb][d][s] = M_in[mb][s][d] (self-owned, normal)
  {
    const int d_l = tid >> 3, sq = tid & 7;
    const int d = mdh * 32 + d_l;
#pragma unroll 4
    for (int j = 0; j < 16; ++j) {
      const int s = sq * 16 + j;
      Mws[(mb * DD + d) * SS + s] = M_in[(mb * SS + s) * DD + d];
    }
  }

  // read-LSTM step 0: hr_1 = cell(emb[0], hr0)
  {
    const int h = tid >> 7, cl = (tid >> 4) & 7, b = tid & 15;
    const int col = (cl >> 1) * DD + dr0 + (cl & 1);
    float acc;
    if (h == 0) acc = dotf4(emb + b * DD, Wih_r + col * DD, DD / 4);
    else        acc = dotf4(hr0 + b * DD, Whh_r + col * DD, DD / 4);
    gsave[tid] = acc;
  }
  __syncthreads();
  if (tid >= 128 && tid < 160) {
    const int t = tid - 128, b = t & 15, dl = t >> 4;
    float g[4];
#pragma unroll
    for (int q = 0; q < 4; ++q) {
      const int cl = q * 2 + dl, col = q * DD + dr0 + dl;
      g[q] = gsave[cl * 16 + b] + gsave[128 + cl * 16 + b] + bih_r[col] + bhh_r[col];
    }
    cr = sigf(g[1]) * cr + sigf(g[0]) * tanhf(g[2]);
    const float h2 = sigf(g[3]) * tanhf(cr);
    stg(hrr + 1 * BD + b * DD + dr0 + dl, h2);
  }
  lbar(cntp, ep);

  // =========================== MAIN LOOP ===========================
  for (int i = 0; i < TT; ++i) {
    const float* hr_i1 = hrr + (i + 1) * BD;   // hr_{i+1}
    const int ii = i + 1;                      // read-LSTM step index this phase

    // ---------------- Phase A: read-LSTM dots + mat-M_i + sim partials ----------------
    if (ii < TT) {
      const int h = tid >> 7, cl = (tid >> 4) & 7, b = tid & 15;
      const int col = (cl >> 1) * DD + dr0 + (cl & 1);
      float acc;
      if (h == 0) acc = dotf4(emb + (ii * BB + b) * DD, Wih_r + col * DD, DD / 4);
      else        acc = dotf4(hr_i1 + b * DD,           Whh_r + col * DD, DD / 4);
      gsave[tid] = acc;
    }
    {
      const int d_l = tid >> 3, sq = tid & 7;
      const int d = mdh * 32 + d_l;
      float* Mrow = Mws + (mb * DD + d) * SS;
      const float hrv = hr_i1[mb * DD + d];
      float4 sim4[4];
      if (i > 0) {
        const float hwv = hwr[i * BD + mb * DD + d];
#pragma unroll
        for (int j = 0; j < 4; ++j) {
          const int s4 = sq * 16 + j * 4;
          float4 M4 = *(float4*)(Mrow + s4);
          float4 z4 = *(const float4*)(z_lds + s4);
          M4.x = (1.f - z4.x) * (M4.x + hwv);
          M4.y = (1.f - z4.y) * (M4.y + hwv);
          M4.z = (1.f - z4.z) * (M4.z + hwv);
          M4.w = (1.f - z4.w) * (M4.w + hwv);
          *(float4*)(Mrow + s4) = M4;
          sim4[j].x = hrv * M4.x; sim4[j].y = hrv * M4.y;
          sim4[j].z = hrv * M4.z; sim4[j].w = hrv * M4.w;
        }
      } else {
#pragma unroll
        for (int j = 0; j < 4; ++j) {
          const int s4 = sq * 16 + j * 4;
          float4 M4 = *(const float4*)(Mrow + s4);
          sim4[j].x = hrv * M4.x; sim4[j].y = hrv * M4.y;
          sim4[j].z = hrv * M4.z; sim4[j].w = hrv * M4.w;
        }
      }
#pragma unroll
      for (int j = 0; j < 4; ++j)
        *(float4*)(scr + d_l * 132 + sq * 16 + j * 4) = sim4[j];
    }
    __syncthreads();
    // sim reduce over 32 d-rows -> sc1 sim partials
    if (tid < SS) {
      float v = 0.f;
#pragma unroll
      for (int dl2 = 0; dl2 < 32; ++dl2) v += scr[dl2 * 132 + tid];
      stg(sp + (mb * 16 + mdh) * SS + tid, v);
    }
    // read-LSTM cell finalize -> hr_{i+2}
    if (ii < TT && tid >= 128 && tid < 160) {
      const int t = tid - 128, b = t & 15, dl = t >> 4;
      float g[4];
#pragma unroll
      for (int q = 0; q < 4; ++q) {
        const int cl = q * 2 + dl, col = q * DD + dr0 + dl;
        g[q] = gsave[cl * 16 + b] + gsave[128 + cl * 16 + b] + bih_r[col] + bhh_r[col];
      }
      cr = sigf(g[1]) * cr + sigf(g[0]) * tanhf(g[2]);
      const float h2 = sigf(g[3]) * tanhf(cr);
      stg(hrr + (ii + 1) * BD + b * DD + dr0 + dl, h2);
      if (ii == TT - 1) {
        out[OUT_HR + b * DD + dr0 + dl] = h2;
        out[OUT_CR + b * DD + dr0 + dl] = cr;
      }
    }
    lbar(cntp, ep);

    // ---------------- Phase B: softmax (redundant per slice-block) + m slice + g_hr ----------------
    {
      float v = 0.f, e = 0.f;
      if (tid < SS) {
#pragma unroll
        for (int j = 0; j < 16; ++j) v += ldga(sp + (mb * 16 + j) * SS + tid);
        float wm = v;
        for (int off = 32; off > 0; off >>= 1) wm = fmaxf(wm, __shfl_xor(wm, off));
        if ((tid & 63) == 0) scr[4224 + (tid >> 6)] = wm;
      }
      __syncthreads();
      if (tid < SS) {
        const float gmax = fmaxf(scr[4224], scr[4225]);
        e = __expf(v - gmax);
        float sm = e;
        for (int off = 32; off > 0; off >>= 1) sm += __shfl_xor(sm, off);
        if ((tid & 63) == 0) scr[4226 + (tid >> 6)] = sm;
      }
      __syncthreads();
      if (tid < SS) z_lds[tid] = e / (scr[4226] + scr[4227]);
    }
    __syncthreads();
    // m slice: m[mb][d] = sum_s z[s]*M_i[mb][d][s]  (slice is L1/L2-hot)
    {
      const int d_l = tid >> 3, sq = tid & 7;
      const int d = mdh * 32 + d_l;
      const float* Mrow = Mws + (mb * DD + d) * SS;
      const float4* zr = (const float4*)(z_lds + sq * 16);
      const float4* Mr = (const float4*)(Mrow + sq * 16);
      float mv = 0.f;
#pragma unroll
      for (int j = 0; j < 4; ++j) {
        float4 z4 = zr[j], M4 = Mr[j];
        mv = fmaf(z4.x, M4.x, mv); mv = fmaf(z4.y, M4.y, mv);
        mv = fmaf(z4.z, M4.z, mv); mv = fmaf(z4.w, M4.w, mv);
      }
      scr[d_l * 8 + sq] = mv;
    }
    // g_hr partials: gates over hr half of Wfused (kept in LDS for phase C)
    {
      const int kh = tid >> 7, bo = (tid >> 6) & 1, c = (tid >> 3) & 7, bl = tid & 7;
      const int b = bo * 8 + bl;
      const int col = (c >> 1) * DD + dr0 + (c & 1);
      gsave[tid] = dotf4(hr_i1 + b * DD + kh * 256, WF + col * 1024 + kh * 256, 64);
    }
    __syncthreads();
    if (tid < 32) {
      float mv = 0.f;
#pragma unroll
      for (int j = 0; j < 8; ++j) mv += scr[tid * 8 + j];
      stg(mr + i * BD + mb * DD + mdh * 32 + tid, mv);
    }
    lbar(cntp, ep);

    // ---------------- Phase C: g_m + g_hw + write-LSTM cell ----------------
    {
      const int kh = tid >> 7, bo = (tid >> 6) & 1, c = (tid >> 3) & 7, bl = tid & 7;
      const int b = bo * 8 + bl;
      const int col = (c >> 1) * DD + dr0 + (c & 1);
      const float* hwsrc = (i == 0) ? hw0 : (hwr + i * BD);
      float acc = dotf4(mr + i * BD + b * DD + kh * 256, WF + col * 1024 + 512 + kh * 256, 64)
                + dotf4(hwsrc + b * DD + kh * 256,       Whh_w + col * DD + kh * 256, 64);
      scr[tid] = acc;
    }
    __syncthreads();
    if (tid >= 128 && tid < 160) {
      const int t = tid - 128, b = t & 15, dl = t >> 4;
      const int bo = b >> 3, bl = b & 7;
      float g[4];
#pragma unroll
      for (int q = 0; q < 4; ++q) {
        const int c = q * 2 + dl;
        const int idx = bo * 64 + c * 8 + bl;
        g[q] = gsave[idx] + gsave[128 + idx] + scr[idx] + scr[128 + idx] + bfl[c];
      }
      cw = sigf(g[1]) * cw + sigf(g[0]) * tanhf(g[2]);
      const float h2 = sigf(g[3]) * tanhf(cw);
      const int d = dr0 + dl;
      stg(hwr + (i + 1) * BD + b * DD + d, h2);
      out[i * BD + b * DD + d] = h2;
      if (i == TT - 1) {
        out[OUT_HW + b * DD + d] = h2;
        out[OUT_CW + b * DD + d] = cw;
      }
    }
    lbar(cntp, ep);
  }

  // =========================== EPILOGUE: final M update + output ===========================
  {
    const int d_l = tid >> 3, sq = tid & 7;
    const int d = mdh * 32 + d_l;
    const float hwv = hwr[TT * BD + mb * DD + d];   // hw_64 (sc1-written, post-barrier)
    const float* Mrow = Mws + (mb * DD + d) * SS;
#pragma unroll 4
    for (int j = 0; j < 16; ++j) {
      const int s = sq * 16 + j;
      const float nv = (1.f - z_lds[s]) * (Mrow[s] + hwv);
      out[OUT_MF + (mb * SS + s) * DD + d] = nv;
    }
  }
}

extern "C" void kernel_launch(void* const* d_in, const int* in_sizes, int n_in,
                              void* d_out, int out_size, void* d_ws, size_t ws_size,
                              hipStream_t stream) {
  (void)in_sizes; (void)n_in; (void)out_size; (void)ws_size;
  const float* emb   = (const float*)d_in[0];
  const float* M_in  = (const float*)d_in[1];
  const float* hr0   = (const float*)d_in[2];
  const float* cr0   = (const float*)d_in[3];
  const float* hw0   = (const float*)d_in[4];
  const float* cw0   = (const float*)d_in[5];
  const float* Wih_r = (const float*)d_in[6];
  const float* Whh_r = (const float*)d_in[7];
  const float* bih_r = (const float*)d_in[8];
  const float* bhh_r = (const float*)d_in[9];
  const float* Wih_w = (const float*)d_in[10];
  const float* Whh_w = (const float*)d_in[11];
  const float* bih_w = (const float*)d_in[12];
  const float* bhh_w = (const float*)d_in[13];
  const float* Wc    = (const float*)d_in[14];
  const float* bc    = (const float*)d_in[15];
  float* out = (float*)d_out;

  char* wsb = (char*)d_ws;
  unsigned* flagp = (unsigned*)wsb;          // byte 0
  unsigned* cntp  = (unsigned*)(wsb + 256);  // separate cacheline
  float* wsf = (float*)(wsb + 1024);         // ~19.1 MB used

  hipLaunchKernelGGL(memnet, dim3(NBLK), dim3(NTH), 0, stream,
                     emb, M_in, hr0, cr0, hw0, cw0,
                     Wih_r, Whh_r, bih_r, bhh_r,
                     Wih_w, Whh_w, bih_w, bhh_w, Wc, bc,
                     out, flagp, cntp, wsf);
}

// Round 3
// 3902.216 us; speedup vs baseline: 2.1455x; 1.0049x over previous
//
#include <hip/hip_runtime.h>
#include <math.h>

// Problem constants (fixed by setup_inputs)
#define TT 64
#define BB 16
#define SS 128
#define DD 512
#define NBLK 256          // compute blocks; +1 leader block
#define NTH 256
#define BD (BB*DD)               // 8192
#define OUT_HR   (TT*BD)         // 524288
#define OUT_CR   (OUT_HR + BD)
#define OUT_HW   (OUT_CR + BD)
#define OUT_CW   (OUT_HW + BD)
#define OUT_MF   (OUT_CW + BD)   // 557056
#define MAGIC 0x13579BDFu
#define EPMAX (1 + 3*TT)         // 193 barrier epochs

// workspace float offsets (after 40960-byte header)
#define WF_OFF   0            // Wfused [2048][1024]            = 2,097,152
#define MW_OFF   2097152      // M transposed [16][512][128]    = 1,048,576
#define HRR_OFF  3145728      // hr ring [65][16][512]          =   532,480
#define HWR_OFF  3678208      // hw ring [65][16][512]          =   532,480
#define MR_OFF   4210688      // m ring  [64][16][512]          =   524,288
#define SP_OFF   4734976      // sim partials [16][16][128]     =    32,768

__device__ __forceinline__ float sigf(float x) { return 1.f / (1.f + __expf(-x)); }

// agent-scope (sc1) store/load for cross-block data
__device__ __forceinline__ void stg(float* p, float v) {
  __hip_atomic_store(p, v, __ATOMIC_RELAXED, __HIP_MEMORY_SCOPE_AGENT);
}
__device__ __forceinline__ float ldga(const float* p) {
  return __hip_atomic_load(p, __ATOMIC_RELAXED, __HIP_MEMORY_SCOPE_AGENT);
}
__device__ __forceinline__ void stg_u(unsigned* p, unsigned v) {
  __hip_atomic_store(p, v, __ATOMIC_RELAXED, __HIP_MEMORY_SCOPE_AGENT);
}
__device__ __forceinline__ unsigned ldg_u(const unsigned* p) {
  return __hip_atomic_load(p, __ATOMIC_RELAXED, __HIP_MEMORY_SCOPE_AGENT);
}

#define SLOT_STRIDE 32   // dwords: one 128B line per block slot
#define RF_STRIDE   32   // dwords: 8 replicated release lines

// arrive: drain own stores (compiler also drains all waves at s_barrier), post epoch
__device__ __forceinline__ void barrive(unsigned* slots, int bid, unsigned ep) {
  __syncthreads();   // compiler emits s_waitcnt vmcnt(0) before s_barrier -> all waves drained
  if (threadIdx.x == 0) {
    asm volatile("s_waitcnt vmcnt(0)" ::: "memory");
    stg_u(slots + bid * SLOT_STRIDE, ep);
  }
}
// wait: spin on replicated release flag
__device__ __forceinline__ void bwait(const unsigned* rflags, int bid, unsigned ep) {
  if (threadIdx.x == 0) {
    const unsigned* p = rflags + (bid & 7) * RF_STRIDE;
    while (ldg_u(p) < ep) __builtin_amdgcn_s_sleep(1);
  }
  __syncthreads();
}

__device__ __forceinline__ float dotf4(const float* __restrict__ a,
                                       const float* __restrict__ b, int n4) {
  const float4* a4 = (const float4*)a;
  const float4* b4 = (const float4*)b;
  float4 s = make_float4(0.f, 0.f, 0.f, 0.f);
#pragma unroll 8
  for (int k = 0; k < n4; ++k) {
    float4 x = a4[k], y = b4[k];
    s.x = fmaf(x.x, y.x, s.x); s.y = fmaf(x.y, y.y, s.y);
    s.z = fmaf(x.z, y.z, s.z); s.w = fmaf(x.w, y.w, s.w);
  }
  return (s.x + s.y) + (s.z + s.w);
}

__global__ void __launch_bounds__(NTH) memnet(
    const float* __restrict__ emb, const float* __restrict__ M_in,
    const float* __restrict__ hr0, const float* __restrict__ cr0,
    const float* __restrict__ hw0, const float* __restrict__ cw0,
    const float* __restrict__ Wih_r, const float* __restrict__ Whh_r,
    const float* __restrict__ bih_r, const float* __restrict__ bhh_r,
    const float* __restrict__ Wih_w, const float* __restrict__ Whh_w,
    const float* __restrict__ bih_w, const float* __restrict__ bhh_w,
    const float* __restrict__ Wc, const float* __restrict__ bc,
    float* __restrict__ out,
    unsigned* flagp, unsigned* rflags, unsigned* slots, float* __restrict__ wsf)
{
  const int tid = threadIdx.x;
  const int bid = blockIdx.x;

  // ---------------- leader block: init + barrier release engine ----------------
  if (bid == NBLK) {
    for (int s = tid; s < NBLK; s += NTH) stg_u(slots + s * SLOT_STRIDE, 0u);
    if (tid < 8) stg_u(rflags + tid * RF_STRIDE, 0u);
    asm volatile("s_waitcnt vmcnt(0)" ::: "memory");
    __syncthreads();
    if (tid == 0) stg_u(flagp, MAGIC);
    if (tid < 64) {  // wave 0 polls; lanes 0..63 each own 4 slots
      for (unsigned ep = 1; ep <= (unsigned)EPMAX; ++ep) {
        for (;;) {
          unsigned mn = 0xffffffffu;
#pragma unroll
          for (int j = 0; j < 4; ++j)
            mn = min(mn, ldg_u(slots + (tid + 64 * j) * SLOT_STRIDE));
          if (__all(mn >= ep)) break;
        }
        if (tid < 8) stg_u(rflags + tid * RF_STRIDE, ep);
      }
    }
    return;
  }

  // roles (every compute block has all three):
  const int mb  = bid & 15;          // M-slice batch
  const int mdh = bid >> 4;          // M-slice d-chunk: d in [mdh*32, mdh*32+32)
  const int dr0 = 2 * bid;           // read/write-LSTM hidden dims {dr0, dr0+1}

  float* WF  = wsf + WF_OFF;
  float* Mws = wsf + MW_OFF;
  float* hrr = wsf + HRR_OFF;
  float* hwr = wsf + HWR_OFF;
  float* mr  = wsf + MR_OFF;
  float* sp  = wsf + SP_OFF;

  __shared__ float z_lds[SS];        // persistent z_i for own mb
  __shared__ float scr[4352];        // A: sim partials [32][132]; B/C scratch; [4224..] scalars
  __shared__ float gsave[256];       // A: rl partials; B->C: g_hr partials
  __shared__ float bfl[8];           // fused write bias for own 8 cols
  __shared__ float wih_lds[8 * DD];  // prologue: Wih_w rows for own 8 cols

  // wait for leader init (slots/rflags zeroed) before any arrive
  if (tid == 0) {
    while (ldg_u(flagp) != MAGIC) __builtin_amdgcn_s_sleep(1);
  }
  __syncthreads();
  unsigned ep = 0;

  // persistent cell states on threads [128,160): t=tid-128 -> (b=t&15, dl=t>>4)
  float cr = 0.f, cw = 0.f;
  if (tid >= 128 && tid < 160) {
    const int t = tid - 128, b = t & 15, dl = t >> 4;
    cr = cr0[b * DD + dr0 + dl];
    cw = cw0[b * DD + dr0 + dl];
  }

  // =========================== PROLOGUE ===========================
  {
    const float2* src;
#pragma unroll
    for (int c = 0; c < 8; ++c) {
      const int col = (c >> 1) * DD + dr0 + (c & 1);
      src = (const float2*)(Wih_w + col * DD);
      ((float2*)(wih_lds + c * DD))[tid] = src[tid];
    }
  }
  __syncthreads();

  // Wfused[col][k] = sum_c Wih_w[col][c] * Wc[c][k]  (own 8 cols; self-consumed -> normal stores)
  {
    float4 acc[8];
#pragma unroll
    for (int c = 0; c < 8; ++c) acc[c] = make_float4(0.f, 0.f, 0.f, 0.f);
    const int k0 = tid * 4;
    for (int cc = 0; cc < DD; ++cc) {
      float4 wc4 = *(const float4*)(Wc + cc * 1024 + k0);
#pragma unroll
      for (int c = 0; c < 8; ++c) {
        const float wv = wih_lds[c * DD + cc];
        acc[c].x = fmaf(wv, wc4.x, acc[c].x);
        acc[c].y = fmaf(wv, wc4.y, acc[c].y);
        acc[c].z = fmaf(wv, wc4.z, acc[c].z);
        acc[c].w = fmaf(wv, wc4.w, acc[c].w);
      }
    }
#pragma unroll
    for (int c = 0; c < 8; ++c) {
      const int col = (c >> 1) * DD + dr0 + (c & 1);
      *(float4*)(WF + col * 1024 + k0) = acc[c];
    }
  }
  // bfused[c] = bih_w + bhh_w + Wih_w[col,:]·bc
  if (tid < 8) {
    const int col = (tid >> 1) * DD + dr0 + (tid & 1);
    float s = 0.f;
    for (int cc = 0; cc < DD; ++cc) s = fmaf(wih_lds[tid * DD + cc], bc[cc], s);
    bfl[tid] = s + bih_w[col] + bhh_w[col];
  }

  // transpose own M slice: Mws[mb][d][s] = M_in[mb][s][d] (self-owned, normal)
  {
    const int d_l = tid >> 3, sq = tid & 7;
    const int d = mdh * 32 + d_l;
#pragma unroll 4
    for (int j = 0; j < 16; ++j) {
      const int s = sq * 16 + j;
      Mws[(mb * DD + d) * SS + s] = M_in[(mb * SS + s) * DD + d];
    }
  }

  // read-LSTM step 0: hr_1 = cell(emb[0], hr0)
  {
    const int h = tid >> 7, cl = (tid >> 4) & 7, b = tid & 15;
    const int col = (cl >> 1) * DD + dr0 + (cl & 1);
    float acc;
    if (h == 0) acc = dotf4(emb + b * DD, Wih_r + col * DD, DD / 4);
    else        acc = dotf4(hr0 + b * DD, Whh_r + col * DD, DD / 4);
    gsave[tid] = acc;
  }
  __syncthreads();
  if (tid >= 128 && tid < 160) {
    const int t = tid - 128, b = t & 15, dl = t >> 4;
    float g[4];
#pragma unroll
    for (int q = 0; q < 4; ++q) {
      const int cl = q * 2 + dl, col = q * DD + dr0 + dl;
      g[q] = gsave[cl * 16 + b] + gsave[128 + cl * 16 + b] + bih_r[col] + bhh_r[col];
    }
    cr = sigf(g[1]) * cr + sigf(g[0]) * tanhf(g[2]);
    const float h2 = sigf(g[3]) * tanhf(cr);
    stg(hrr + 1 * BD + b * DD + dr0 + dl, h2);
  }
  barrive(slots, bid, ++ep);
  bwait(rflags, bid, ep);

  // =========================== MAIN LOOP ===========================
  for (int i = 0; i < TT; ++i) {
    const float* hr_i1 = hrr + (i + 1) * BD;   // hr_{i+1}
    const int ii = i + 1;                      // read-LSTM step this phase

    // ---- Phase A exposed: M-update + sim partials -> sp (cross-block) ----
    {
      const int d_l = tid >> 3, sq = tid & 7;
      const int d = mdh * 32 + d_l;
      float* Mrow = Mws + (mb * DD + d) * SS;
      const float hrv = hr_i1[mb * DD + d];
      float4 sim4[4];
      if (i > 0) {
        const float hwv = hwr[i * BD + mb * DD + d];
#pragma unroll
        for (int j = 0; j < 4; ++j) {
          const int s4 = sq * 16 + j * 4;
          float4 M4 = *(float4*)(Mrow + s4);
          float4 z4 = *(const float4*)(z_lds + s4);
          M4.x = (1.f - z4.x) * (M4.x + hwv);
          M4.y = (1.f - z4.y) * (M4.y + hwv);
          M4.z = (1.f - z4.z) * (M4.z + hwv);
          M4.w = (1.f - z4.w) * (M4.w + hwv);
          *(float4*)(Mrow + s4) = M4;
          sim4[j].x = hrv * M4.x; sim4[j].y = hrv * M4.y;
          sim4[j].z = hrv * M4.z; sim4[j].w = hrv * M4.w;
        }
      } else {
#pragma unroll
        for (int j = 0; j < 4; ++j) {
          const int s4 = sq * 16 + j * 4;
          float4 M4 = *(const float4*)(Mrow + s4);
          sim4[j].x = hrv * M4.x; sim4[j].y = hrv * M4.y;
          sim4[j].z = hrv * M4.z; sim4[j].w = hrv * M4.w;
        }
      }
#pragma unroll
      for (int j = 0; j < 4; ++j)
        *(float4*)(scr + d_l * 132 + sq * 16 + j * 4) = sim4[j];
    }
    __syncthreads();
    if (tid < SS) {
      float v = 0.f;
#pragma unroll
      for (int dl2 = 0; dl2 < 32; ++dl2) v += scr[dl2 * 132 + tid];
      stg(sp + (mb * 16 + mdh) * SS + tid, v);
    }
    barrive(slots, bid, ++ep);

    // ---- Phase A hidden: read-LSTM step ii (consumed 2 barriers later) ----
    if (ii < TT) {
      {
        const int h = tid >> 7, cl = (tid >> 4) & 7, b = tid & 15;
        const int col = (cl >> 1) * DD + dr0 + (cl & 1);
        float acc;
        if (h == 0) acc = dotf4(emb + (ii * BB + b) * DD, Wih_r + col * DD, DD / 4);
        else        acc = dotf4(hr_i1 + b * DD,           Whh_r + col * DD, DD / 4);
        gsave[tid] = acc;
      }
      __syncthreads();
      if (tid >= 128 && tid < 160) {
        const int t = tid - 128, b = t & 15, dl = t >> 4;
        float g[4];
#pragma unroll
        for (int q = 0; q < 4; ++q) {
          const int cl = q * 2 + dl, col = q * DD + dr0 + dl;
          g[q] = gsave[cl * 16 + b] + gsave[128 + cl * 16 + b] + bih_r[col] + bhh_r[col];
        }
        cr = sigf(g[1]) * cr + sigf(g[0]) * tanhf(g[2]);
        const float h2 = sigf(g[3]) * tanhf(cr);
        stg(hrr + (ii + 1) * BD + b * DD + dr0 + dl, h2);
        if (ii == TT - 1) {
          out[OUT_HR + b * DD + dr0 + dl] = h2;
          out[OUT_CR + b * DD + dr0 + dl] = cr;
        }
      }
    }
    bwait(rflags, bid, ep);

    // ---- Phase B exposed: softmax + m slice -> mr (cross-block) ----
    {
      float v = 0.f, e = 0.f;
      if (tid < SS) {
#pragma unroll
        for (int j = 0; j < 16; ++j) v += ldga(sp + (mb * 16 + j) * SS + tid);
        float wm = v;
        for (int off = 32; off > 0; off >>= 1) wm = fmaxf(wm, __shfl_xor(wm, off));
        if ((tid & 63) == 0) scr[4224 + (tid >> 6)] = wm;
      }
      __syncthreads();
      if (tid < SS) {
        const float gmax = fmaxf(scr[4224], scr[4225]);
        e = __expf(v - gmax);
        float sm = e;
        for (int off = 32; off > 0; off >>= 1) sm += __shfl_xor(sm, off);
        if ((tid & 63) == 0) scr[4226 + (tid >> 6)] = sm;
      }
      __syncthreads();
      if (tid < SS) z_lds[tid] = e / (scr[4226] + scr[4227]);
    }
    __syncthreads();
    {
      const int d_l = tid >> 3, sq = tid & 7;
      const int d = mdh * 32 + d_l;
      const float* Mrow = Mws + (mb * DD + d) * SS;
      const float4* zr = (const float4*)(z_lds + sq * 16);
      const float4* Mr = (const float4*)(Mrow + sq * 16);
      float mv = 0.f;
#pragma unroll
      for (int j = 0; j < 4; ++j) {
        float4 z4 = zr[j], M4 = Mr[j];
        mv = fmaf(z4.x, M4.x, mv); mv = fmaf(z4.y, M4.y, mv);
        mv = fmaf(z4.z, M4.z, mv); mv = fmaf(z4.w, M4.w, mv);
      }
      scr[d_l * 8 + sq] = mv;
    }
    __syncthreads();
    if (tid < 32) {
      float mv = 0.f;
#pragma unroll
      for (int j = 0; j < 8; ++j) mv += scr[tid * 8 + j];
      stg(mr + i * BD + mb * DD + mdh * 32 + tid, mv);
    }
    barrive(slots, bid, ++ep);

    // ---- Phase B hidden: g_hr partials (block-local, LDS) ----
    {
      const int kh = tid >> 7, bo = (tid >> 6) & 1, c = (tid >> 3) & 7, bl = tid & 7;
      const int b = bo * 8 + bl;
      const int col = (c >> 1) * DD + dr0 + (c & 1);
      gsave[tid] = dotf4(hr_i1 + b * DD + kh * 256, WF + col * 1024 + kh * 256, 64);
    }
    bwait(rflags, bid, ep);

    // ---- Phase C: g_m + g_hw + write-LSTM cell ----
    {
      const int kh = tid >> 7, bo = (tid >> 6) & 1, c = (tid >> 3) & 7, bl = tid & 7;
      const int b = bo * 8 + bl;
      const int col = (c >> 1) * DD + dr0 + (c & 1);
      const float* hwsrc = (i == 0) ? hw0 : (hwr + i * BD);
      float acc = dotf4(mr + i * BD + b * DD + kh * 256, WF + col * 1024 + 512 + kh * 256, 64)
                + dotf4(hwsrc + b * DD + kh * 256,       Whh_w + col * DD + kh * 256, 64);
      scr[tid] = acc;
    }
    __syncthreads();
    if (tid >= 128 && tid < 160) {
      const int t = tid - 128, b = t & 15, dl = t >> 4;
      const int bo = b >> 3, bl = b & 7;
      float g[4];
#pragma unroll
      for (int q = 0; q < 4; ++q) {
        const int c = q * 2 + dl;
        const int idx = bo * 64 + c * 8 + bl;
        g[q] = gsave[idx] + gsave[128 + idx] + scr[idx] + scr[128 + idx] + bfl[c];
      }
      cw = sigf(g[1]) * cw + sigf(g[0]) * tanhf(g[2]);
      const float h2 = sigf(g[3]) * tanhf(cw);
      const int d = dr0 + dl;
      stg(hwr + (i + 1) * BD + b * DD + d, h2);
      out[i * BD + b * DD + d] = h2;
      if (i == TT - 1) {
        out[OUT_HW + b * DD + d] = h2;
        out[OUT_CW + b * DD + d] = cw;
      }
    }
    barrive(slots, bid, ++ep);
    bwait(rflags, bid, ep);
  }

  // =========================== EPILOGUE: final M output ===========================
  {
    const int d_l = tid >> 3, sq = tid & 7;
    const int d = mdh * 32 + d_l;
    const float hwv = hwr[TT * BD + mb * DD + d];   // hw_64
    const float* Mrow = Mws + (mb * DD + d) * SS;
#pragma unroll 4
    for (int j = 0; j < 16; ++j) {
      const int s = sq * 16 + j;
      const float nv = (1.f - z_lds[s]) * (Mrow[s] + hwv);
      out[OUT_MF + (mb * SS + s) * DD + d] = nv;
    }
  }
}

extern "C" void kernel_launch(void* const* d_in, const int* in_sizes, int n_in,
                              void* d_out, int out_size, void* d_ws, size_t ws_size,
                              hipStream_t stream) {
  (void)in_sizes; (void)n_in; (void)out_size; (void)ws_size;
  const float* emb   = (const float*)d_in[0];
  const float* M_in  = (const float*)d_in[1];
  const float* hr0   = (const float*)d_in[2];
  const float* cr0   = (const float*)d_in[3];
  const float* hw0   = (const float*)d_in[4];
  const float* cw0   = (const float*)d_in[5];
  const float* Wih_r = (const float*)d_in[6];
  const float* Whh_r = (const float*)d_in[7];
  const float* bih_r = (const float*)d_in[8];
  const float* bhh_r = (const float*)d_in[9];
  const float* Wih_w = (const float*)d_in[10];
  const float* Whh_w = (const float*)d_in[11];
  const float* bih_w = (const float*)d_in[12];
  const float* bhh_w = (const float*)d_in[13];
  const float* Wc    = (const float*)d_in[14];
  const float* bc    = (const float*)d_in[15];
  float* out = (float*)d_out;

  char* wsb = (char*)d_ws;
  unsigned* flagp  = (unsigned*)wsb;              // MAGIC line
  unsigned* rflags = (unsigned*)(wsb + 1024);     // 8 x 128B release lines
  unsigned* slots  = (unsigned*)(wsb + 4096);     // 256 x 128B arrival slots
  float* wsf = (float*)(wsb + 40960);             // ~19.1 MB data region

  hipLaunchKernelGGL(memnet, dim3(NBLK + 1), dim3(NTH), 0, stream,
                     emb, M_in, hr0, cr0, hw0, cw0,
                     Wih_r, Whh_r, bih_r, bhh_r,
                     Wih_w, Whh_w, bih_w, bhh_w, Wc, bc,
                     out, flagp, rflags, slots, wsf);
}

// Round 4
// 1845.974 us; speedup vs baseline: 4.5353x; 2.1139x over previous
//
#include <hip/hip_runtime.h>
#include <math.h>

// Problem constants (fixed by setup_inputs)
#define TT 64
#define BB 16
#define SS 128
#define DD 512
#define NBLK 256
#define NTH 256
#define BD (BB*DD)               // 8192
#define OUT_HR   (TT*BD)         // 524288
#define OUT_CR   (OUT_HR + BD)
#define OUT_HW   (OUT_CR + BD)
#define OUT_CW   (OUT_HW + BD)
#define OUT_MF   (OUT_CW + BD)   // 557056
#define MAGIC 0x13579BDFu

// workspace float offsets (after 1024-byte header)
#define HRR_OFF 0              // hr ring [65][16][512]
#define HWR_OFF 532480         // hw ring [65][16][512]
#define MR_OFF  1064960        // m ring  [64][16][512]
#define SP_OFF  1589248        // sim partials [16][16][128]
#define GE_OFF  1622016        // gE [256 blk][64 t][16 b][8 c] = 2M floats

// LDS float offsets (dynamic, ~144 KB)
#define OFF_WHR  0             // Whh_r tile [16 kh][8 c][36]        4672
#define OFF_WHW  4672          // Whh_w tile                         4672
#define OFF_WFH  9344          // Wfused hr-half tile                4672
#define OFF_WFM  14016         // Wfused m-half tile                 4672
#define OFF_ABUF 18688         // hr staged, tiled [16 kh][16 b][36] 9472
#define OFF_ML   28160         // M slice [32][128]                  4096
#define OFF_PRED 32256         // shared scratch: 4224 floats
                               //   predAC = +0 [16][132]; predB = +2112 [16][132]
                               //   simP   = +0 [32][132];  mpart = +0 [256]
#define OFF_GFB  36480         // 128 (B-dot reduced, consumed in C)
#define OFF_GFT  36608         // 128 (A/C-dot reduced, same-phase)
#define OFF_ZL   36736         // 128 (persistent z_i)
#define OFF_BFL  36864         // 8   (fused write bias)
#define OFF_SMW  36872         // 8   (softmax wave scratch)
#define LDS_FLOATS 36880
#define LDS_BYTES  (LDS_FLOATS*4)
#define KH_W 292               // weight tile kh-stride (8*36+4: bank-spread)
#define KH_A 592               // abuf kh-stride (16*36+16: bank-spread)

#define COLC(c) (((c) >> 1) * DD + dr0 + ((c) & 1))

__device__ __forceinline__ float sigf(float x) { return 1.f / (1.f + __expf(-x)); }

// agent-scope (sc1) store/load for cross-block data
__device__ __forceinline__ void stg(float* p, float v) {
  __hip_atomic_store(p, v, __ATOMIC_RELAXED, __HIP_MEMORY_SCOPE_AGENT);
}
__device__ __forceinline__ float ldga(const float* p) {
  return __hip_atomic_load(p, __ATOMIC_RELAXED, __HIP_MEMORY_SCOPE_AGENT);
}

// light grid barrier (R2-style; R3 proved the mechanism is not the bottleneck)
__device__ __forceinline__ void lbar(unsigned* cnt, unsigned& ep) {
  __syncthreads();
  if (threadIdx.x == 0) {
    unsigned target = (++ep) * (unsigned)NBLK;
    asm volatile("s_waitcnt vmcnt(0)" ::: "memory");
    __hip_atomic_fetch_add(cnt, 1u, __ATOMIC_RELAXED, __HIP_MEMORY_SCOPE_AGENT);
    while (__hip_atomic_load(cnt, __ATOMIC_RELAXED, __HIP_MEMORY_SCOPE_AGENT) < target) {}
  }
  __syncthreads();
}
// split-phase: arrive only (post count), wait separately
__device__ __forceinline__ void barrive(unsigned* cnt, unsigned& ep) {
  __syncthreads();
  if (threadIdx.x == 0) {
    ++ep;
    asm volatile("s_waitcnt vmcnt(0)" ::: "memory");
    __hip_atomic_fetch_add(cnt, 1u, __ATOMIC_RELAXED, __HIP_MEMORY_SCOPE_AGENT);
  }
}
__device__ __forceinline__ void bwait(unsigned* cnt, unsigned ep) {
  if (threadIdx.x == 0) {
    unsigned target = ep * (unsigned)NBLK;
    while (__hip_atomic_load(cnt, __ATOMIC_RELAXED, __HIP_MEMORY_SCOPE_AGENT) < target) {}
  }
  __syncthreads();
}

__device__ __forceinline__ float dotf4(const float* __restrict__ a,
                                       const float* __restrict__ b, int n4) {
  const float4* a4 = (const float4*)a;
  const float4* b4 = (const float4*)b;
  float4 s = make_float4(0.f, 0.f, 0.f, 0.f);
#pragma unroll 8
  for (int k = 0; k < n4; ++k) {
    float4 x = a4[k], y = b4[k];
    s.x = fmaf(x.x, y.x, s.x); s.y = fmaf(x.y, y.y, s.y);
    s.z = fmaf(x.z, y.z, s.z); s.w = fmaf(x.w, y.w, s.w);
  }
  return (s.x + s.y) + (s.z + s.w);
}

// 8-col register-blocked dot over a 32-float k-chunk; a from LDS, w from tile
__device__ __forceinline__ void dot_pass8(const float* __restrict__ A,  // abuf + kh*KH_A + b*36
                                          const float* __restrict__ W,  // tile + kh*KH_W
                                          float* __restrict__ pout)     // PRED row + b*8
{
  float acc[8] = {0.f,0.f,0.f,0.f,0.f,0.f,0.f,0.f};
#pragma unroll
  for (int j = 0; j < 8; ++j) {
    float4 a4 = *(const float4*)(A + j*4);
#pragma unroll
    for (int c = 0; c < 8; ++c) {
      float4 w4 = *(const float4*)(W + c*36 + j*4);
      acc[c] = fmaf(a4.x, w4.x, acc[c]); acc[c] = fmaf(a4.y, w4.y, acc[c]);
      acc[c] = fmaf(a4.z, w4.z, acc[c]); acc[c] = fmaf(a4.w, w4.w, acc[c]);
    }
  }
  *(float4*)(pout)   = make_float4(acc[0],acc[1],acc[2],acc[3]);
  *(float4*)(pout+4) = make_float4(acc[4],acc[5],acc[6],acc[7]);
}

// 8-col dot over a 64-float chunk; a from GLOBAL row, w from tiles
__device__ __forceinline__ void dot_pass8g(const float* __restrict__ ag, // global row + khq*64
                                           const float* __restrict__ Wb, // tile base
                                           int khq,
                                           float* __restrict__ pout)
{
  float acc[8] = {0.f,0.f,0.f,0.f,0.f,0.f,0.f,0.f};
#pragma unroll
  for (int jj = 0; jj < 2; ++jj) {
    const float* Wt = Wb + (khq*2 + jj)*KH_W;
#pragma unroll
    for (int j = 0; j < 8; ++j) {
      float4 a4 = *(const float4*)(ag + jj*32 + j*4);
#pragma unroll
      for (int c = 0; c < 8; ++c) {
        float4 w4 = *(const float4*)(Wt + c*36 + j*4);
        acc[c] = fmaf(a4.x, w4.x, acc[c]); acc[c] = fmaf(a4.y, w4.y, acc[c]);
        acc[c] = fmaf(a4.z, w4.z, acc[c]); acc[c] = fmaf(a4.w, w4.w, acc[c]);
      }
    }
  }
  *(float4*)(pout)   = make_float4(acc[0],acc[1],acc[2],acc[3]);
  *(float4*)(pout+4) = make_float4(acc[4],acc[5],acc[6],acc[7]);
}

__global__ void __launch_bounds__(NTH) memnet(
    const float* __restrict__ emb, const float* __restrict__ M_in,
    const float* __restrict__ hr0, const float* __restrict__ cr0,
    const float* __restrict__ hw0, const float* __restrict__ cw0,
    const float* __restrict__ Wih_r, const float* __restrict__ Whh_r,
    const float* __restrict__ bih_r, const float* __restrict__ bhh_r,
    const float* __restrict__ Wih_w, const float* __restrict__ Whh_w,
    const float* __restrict__ bih_w, const float* __restrict__ bhh_w,
    const float* __restrict__ Wc, const float* __restrict__ bc,
    float* __restrict__ out,
    unsigned* flagp, unsigned* cntp, float* __restrict__ wsf)
{
  extern __shared__ float L[];
  const int tid = threadIdx.x;
  const int bid = blockIdx.x;

  // roles (every block has all three)
  const int mb  = bid & 15;          // M-slice batch
  const int mdh = bid >> 4;          // M-slice d-chunk: d in [mdh*32, +32)
  const int dr0 = 2 * bid;           // owned hidden dims {dr0, dr0+1}

  float* hrr = wsf + HRR_OFF;
  float* hwr = wsf + HWR_OFF;
  float* mr  = wsf + MR_OFF;
  float* sp  = wsf + SP_OFF;
  float* gE  = wsf + GE_OFF + bid * (TT * 128);

  // ---- init handshake ----
  if (bid == 0) {
    if (tid == 0) {
      __hip_atomic_store(cntp, 0u, __ATOMIC_RELAXED, __HIP_MEMORY_SCOPE_AGENT);
      asm volatile("s_waitcnt vmcnt(0)" ::: "memory");
      __hip_atomic_store(flagp, MAGIC, __ATOMIC_RELAXED, __HIP_MEMORY_SCOPE_AGENT);
    }
  } else if (tid == 0) {
    while (__hip_atomic_load(flagp, __ATOMIC_RELAXED, __HIP_MEMORY_SCOPE_AGENT) != MAGIC) {}
  }
  __syncthreads();
  unsigned ep = 0;

  // persistent cell states on threads [128,160): t -> (b=t&15, dl=t>>4)
  float cr = 0.f, cw = 0.f;
  if (tid >= 128 && tid < 160) {
    const int t = tid - 128, b = t & 15, dl = t >> 4;
    cr = cr0[b * DD + dr0 + dl];
    cw = cw0[b * DD + dr0 + dl];
  }

  // =========================== PROLOGUE ===========================
  // (1) Wih_w rows for own 8 write-cols -> ABUF region (temp flat [8][512])
  {
    float* wih = L + OFF_ABUF;
#pragma unroll
    for (int c = 0; c < 8; ++c)
      ((float2*)(wih + c * DD))[tid] = ((const float2*)(Wih_w + COLC(c) * DD))[tid];
  }
  __syncthreads();
  // (2) Wfused = Wih_w(own cols) @ Wc  -> WFH/WFM tiles; bfl
  {
    const float* wih = L + OFF_ABUF;
    float4 acc[8];
#pragma unroll
    for (int c = 0; c < 8; ++c) acc[c] = make_float4(0.f,0.f,0.f,0.f);
    const int k0 = tid * 4;
    for (int cc = 0; cc < DD; ++cc) {
      float4 wc4 = *(const float4*)(Wc + cc * 1024 + k0);
#pragma unroll
      for (int c = 0; c < 8; ++c) {
        const float wv = wih[c * DD + cc];
        acc[c].x = fmaf(wv, wc4.x, acc[c].x); acc[c].y = fmaf(wv, wc4.y, acc[c].y);
        acc[c].z = fmaf(wv, wc4.z, acc[c].z); acc[c].w = fmaf(wv, wc4.w, acc[c].w);
      }
    }
    const int kk = k0 & 511, kh = kk >> 5, jf = kk & 31;
    float* Tb = L + ((k0 < 512) ? OFF_WFH : OFF_WFM);
#pragma unroll
    for (int c = 0; c < 8; ++c)
      *(float4*)(Tb + kh*KH_W + c*36 + jf) = acc[c];
    if (tid < 8) {
      float s = 0.f;
      for (int cc = 0; cc < DD; ++cc) s = fmaf(wih[tid * DD + cc], bc[cc], s);
      L[OFF_BFL + tid] = s + bih_w[COLC(tid)] + bhh_w[COLC(tid)];
    }
  }
  __syncthreads();   // wih consumed; ABUF free
  // (3) Whh_r / Whh_w -> tiles
  {
    const int c = tid >> 5, r = tid & 31;
    const int kk = r * 16, kh = kk >> 5, jb = (r & 1) * 16;
#pragma unroll
    for (int set = 0; set < 2; ++set) {
      const float* Wsrc = set ? Whh_w : Whh_r;
      float* dst = L + (set ? OFF_WHW : OFF_WHR) + kh*KH_W + c*36 + jb;
      const float* src = Wsrc + COLC(c) * DD + kk;
#pragma unroll
      for (int u = 0; u < 4; ++u)
        *(float4*)(dst + u*4) = *(const float4*)(src + u*4);
    }
  }
  // (4) M slice transpose -> ML
  {
    const int d_l = tid >> 3, sq = tid & 7;
    const int d = mdh * 32 + d_l;
#pragma unroll 4
    for (int j = 0; j < 16; ++j) {
      const int s = sq * 16 + j;
      L[OFF_ML + d_l * 128 + s] = M_in[(mb * SS + s) * DD + d];
    }
  }
  // (5) gE precompute: gE[t][b][c] = emb[t][b]·Wih_r[col] + bih_r + bhh_r (all 64 t)
  {
    const int tH = tid >> 7, b = (tid >> 3) & 15, c = tid & 7;
    const int col = COLC(c);
    const float bias = bih_r[col] + bhh_r[col];
    const float* wrow = Wih_r + col * DD;
    for (int t = tH * 32; t < tH * 32 + 32; ++t) {
      gE[t * 128 + b * 8 + c] = dotf4(emb + (t * BB + b) * DD, wrow, DD / 4) + bias;
    }
  }
  // (6) stage hr0 -> ABUF (tiled)
  __syncthreads();
  {
#pragma unroll
    for (int j = 0; j < 8; ++j) {
      const int idx = j * 256 + tid;        // float4 index 0..2047
      const int b = idx >> 7, k4 = idx & 127;
      const int kh = k4 >> 3, jf = (k4 & 7) * 4;
      float4 v = ((const float4*)hr0)[idx];
      *(float4*)(L + OFF_ABUF + kh*KH_A + b*36 + jf) = v;
    }
  }
  __syncthreads();
  // (7) read-LSTM step 0 -> hr_1
  {
    const int kh = tid >> 4, b = tid & 15;
    dot_pass8(L + OFF_ABUF + kh*KH_A + b*36, L + OFF_WHR + kh*KH_W,
              L + OFF_PRED + kh*132 + b*8);
  }
  __syncthreads();
  if (tid < 128) {
    float s = 0.f;
#pragma unroll
    for (int k2 = 0; k2 < 16; ++k2) s += L[OFF_PRED + k2*132 + tid];
    L[OFF_GFT + tid] = s;
  }
  __syncthreads();
  if (tid >= 128 && tid < 160) {
    const int t = tid - 128, b = t & 15, dl = t >> 4;
    float g[4];
#pragma unroll
    for (int q = 0; q < 4; ++q) {
      const int bc = b * 8 + q * 2 + dl;
      g[q] = L[OFF_GFT + bc] + gE[0 * 128 + bc];
    }
    cr = sigf(g[1]) * cr + sigf(g[0]) * tanhf(g[2]);
    const float h2 = sigf(g[3]) * tanhf(cr);
    stg(hrr + 1 * BD + b * DD + dr0 + dl, h2);
  }
  lbar(cntp, ep);
  // stage hr_1 -> ABUF for step 0
  {
    const float* src = hrr + 1 * BD;
#pragma unroll
    for (int j = 0; j < 8; ++j) {
      const int idx = j * 256 + tid;
      const int b = idx >> 7, k4 = idx & 127;
      const int kh = k4 >> 3, jf = (k4 & 7) * 4;
      float4 v = ((const float4*)src)[idx];
      *(float4*)(L + OFF_ABUF + kh*KH_A + b*36 + jf) = v;
    }
  }
  __syncthreads();

  // =========================== MAIN LOOP ===========================
  for (int i = 0; i < TT; ++i) {
    const int ii = i + 1;   // read-LSTM step computed this phase

    // ---- Phase A exposed: M-update (lazy) + sim partials -> sp ----
    {
      const int d_l = tid >> 3, sq = tid & 7;
      float* Mrow = L + OFF_ML + d_l * 128;
      const float hrv = L[OFF_ABUF + mdh*KH_A + mb*36 + d_l];
      float4 sim4[4];
      if (i > 0) {
        const float hwv = hwr[i * BD + mb * DD + mdh * 32 + d_l];
#pragma unroll
        for (int j = 0; j < 4; ++j) {
          const int s4 = sq * 16 + j * 4;
          float4 M4 = *(float4*)(Mrow + s4);
          float4 z4 = *(const float4*)(L + OFF_ZL + s4);
          M4.x = (1.f - z4.x) * (M4.x + hwv);
          M4.y = (1.f - z4.y) * (M4.y + hwv);
          M4.z = (1.f - z4.z) * (M4.z + hwv);
          M4.w = (1.f - z4.w) * (M4.w + hwv);
          *(float4*)(Mrow + s4) = M4;
          sim4[j].x = hrv * M4.x; sim4[j].y = hrv * M4.y;
          sim4[j].z = hrv * M4.z; sim4[j].w = hrv * M4.w;
        }
      } else {
#pragma unroll
        for (int j = 0; j < 4; ++j) {
          const int s4 = sq * 16 + j * 4;
          float4 M4 = *(const float4*)(Mrow + s4);
          sim4[j].x = hrv * M4.x; sim4[j].y = hrv * M4.y;
          sim4[j].z = hrv * M4.z; sim4[j].w = hrv * M4.w;
        }
      }
#pragma unroll
      for (int j = 0; j < 4; ++j)
        *(float4*)(L + OFF_PRED + d_l*132 + sq*16 + j*4) = sim4[j];
    }
    __syncthreads();
    if (tid < SS) {
      float v = 0.f;
#pragma unroll
      for (int dl2 = 0; dl2 < 32; ++dl2) v += L[OFF_PRED + dl2*132 + tid];
      stg(sp + (mb * 16 + mdh) * SS + tid, v);
    }
    barrive(cntp, ep);

    // ---- Phase A hidden: read-LSTM hr-dot (Whh_r) + cell -> hr_{i+2} ----
    if (ii < TT) {
      {
        const int kh = tid >> 4, b = tid & 15;
        dot_pass8(L + OFF_ABUF + kh*KH_A + b*36, L + OFF_WHR + kh*KH_W,
                  L + OFF_PRED + kh*132 + b*8);
      }
      __syncthreads();
      if (tid < 128) {
        float s = 0.f;
#pragma unroll
        for (int k2 = 0; k2 < 16; ++k2) s += L[OFF_PRED + k2*132 + tid];
        L[OFF_GFT + tid] = s;
      }
      __syncthreads();
      if (tid >= 128 && tid < 160) {
        const int t = tid - 128, b = t & 15, dl = t >> 4;
        float g[4];
#pragma unroll
        for (int q = 0; q < 4; ++q) {
          const int bc = b * 8 + q * 2 + dl;
          g[q] = L[OFF_GFT + bc] + gE[ii * 128 + bc];
        }
        cr = sigf(g[1]) * cr + sigf(g[0]) * tanhf(g[2]);
        const float h2 = sigf(g[3]) * tanhf(cr);
        stg(hrr + (ii + 1) * BD + b * DD + dr0 + dl, h2);
        if (ii == TT - 1) {
          out[OUT_HR + b * DD + dr0 + dl] = h2;
          out[OUT_CR + b * DD + dr0 + dl] = cr;
        }
      }
    }
    bwait(cntp, ep);

    // ---- Phase B exposed: softmax (redundant) + m slice -> mr ----
    {
      float v = 0.f, e = 0.f;
      if (tid < SS) {
#pragma unroll
        for (int j = 0; j < 16; ++j) v += ldga(sp + (mb * 16 + j) * SS + tid);
        float wm = v;
        for (int off = 32; off > 0; off >>= 1) wm = fmaxf(wm, __shfl_xor(wm, off));
        if ((tid & 63) == 0) L[OFF_SMW + (tid >> 6)] = wm;
      }
      __syncthreads();
      if (tid < SS) {
        const float gmax = fmaxf(L[OFF_SMW], L[OFF_SMW + 1]);
        e = __expf(v - gmax);
        float sm = e;
        for (int off = 32; off > 0; off >>= 1) sm += __shfl_xor(sm, off);
        if ((tid & 63) == 0) L[OFF_SMW + 2 + (tid >> 6)] = sm;
      }
      __syncthreads();
      if (tid < SS) L[OFF_ZL + tid] = e / (L[OFF_SMW + 2] + L[OFF_SMW + 3]);
    }
    __syncthreads();
    {
      const int d_l = tid >> 3, sq = tid & 7;
      const float* Mrow = L + OFF_ML + d_l * 128;
      float mv = 0.f;
#pragma unroll
      for (int j = 0; j < 4; ++j) {
        const int s4 = sq * 16 + j * 4;
        float4 z4 = *(const float4*)(L + OFF_ZL + s4);
        float4 M4 = *(const float4*)(Mrow + s4);
        mv = fmaf(z4.x, M4.x, mv); mv = fmaf(z4.y, M4.y, mv);
        mv = fmaf(z4.z, M4.z, mv); mv = fmaf(z4.w, M4.w, mv);
      }
      L[OFF_PRED + d_l * 8 + sq] = mv;
    }
    __syncthreads();
    if (tid < 32) {
      float mv = 0.f;
#pragma unroll
      for (int j = 0; j < 8; ++j) mv += L[OFF_PRED + tid * 8 + j];
      stg(mr + i * BD + mb * DD + mdh * 32 + tid, mv);
    }
    barrive(cntp, ep);

    // ---- Phase B hidden: g_hr partials (hr · WF hr-half) -> predB ----
    {
      const int kh = tid >> 4, b = tid & 15;
      dot_pass8(L + OFF_ABUF + kh*KH_A + b*36, L + OFF_WFH + kh*KH_W,
                L + OFF_PRED + 2112 + kh*132 + b*8);
    }
    bwait(cntp, ep);

    // ---- Phase C: reduce g_hr; m-dot + hw-dot; write cell ----
    if (tid < 128) {
      float s = 0.f;
#pragma unroll
      for (int k2 = 0; k2 < 16; ++k2) s += L[OFF_PRED + 2112 + k2*132 + tid];
      L[OFF_GFB + tid] = s;
    }
    {
      const int src = tid >> 7, khq = (tid >> 4) & 7, b = tid & 15;
      const float* ag;
      const float* Wb;
      if (src == 0) { ag = mr + i * BD + b * DD + khq * 64; Wb = L + OFF_WFM; }
      else {
        const float* hwsrc = (i == 0) ? hw0 : (hwr + i * BD);
        ag = hwsrc + b * DD + khq * 64; Wb = L + OFF_WHW;
      }
      dot_pass8g(ag, Wb, khq, L + OFF_PRED + (src * 8 + khq) * 132 + b * 8);
    }
    __syncthreads();
    if (tid < 128) {
      float s = 0.f;
#pragma unroll
      for (int k2 = 0; k2 < 16; ++k2) s += L[OFF_PRED + k2*132 + tid];
      L[OFF_GFT + tid] = s;
    }
    __syncthreads();
    if (tid >= 128 && tid < 160) {
      const int t = tid - 128, b = t & 15, dl = t >> 4;
      float g[4];
#pragma unroll
      for (int q = 0; q < 4; ++q) {
        const int c = q * 2 + dl, bc = b * 8 + c;
        g[q] = L[OFF_GFB + bc] + L[OFF_GFT + bc] + L[OFF_BFL + c];
      }
      cw = sigf(g[1]) * cw + sigf(g[0]) * tanhf(g[2]);
      const float h2 = sigf(g[3]) * tanhf(cw);
      const int d = dr0 + dl;
      stg(hwr + (i + 1) * BD + b * DD + d, h2);
      out[i * BD + b * DD + d] = h2;
      if (i == TT - 1) {
        out[OUT_HW + b * DD + d] = h2;
        out[OUT_CW + b * DD + d] = cw;
      }
    }
    barrive(cntp, ep);
    // hidden in C's barrier window: stage hr_{i+2} -> ABUF for next step
    if (i < TT - 1) {
      const float* src = hrr + (i + 2) * BD;
#pragma unroll
      for (int j = 0; j < 8; ++j) {
        const int idx = j * 256 + tid;
        const int b = idx >> 7, k4 = idx & 127;
        const int kh = k4 >> 3, jf = (k4 & 7) * 4;
        float4 v = ((const float4*)src)[idx];
        *(float4*)(L + OFF_ABUF + kh*KH_A + b*36 + jf) = v;
      }
    }
    bwait(cntp, ep);
  }

  // =========================== EPILOGUE: final M output ===========================
  {
    const int d_l = tid >> 3, sq = tid & 7;
    const int d = mdh * 32 + d_l;
    const float hwv = hwr[TT * BD + mb * DD + d];
#pragma unroll 4
    for (int j = 0; j < 16; ++j) {
      const int s = sq * 16 + j;
      const float nv = (1.f - L[OFF_ZL + s]) * (L[OFF_ML + d_l * 128 + s] + hwv);
      out[OUT_MF + (mb * SS + s) * DD + d] = nv;
    }
  }
}

extern "C" void kernel_launch(void* const* d_in, const int* in_sizes, int n_in,
                              void* d_out, int out_size, void* d_ws, size_t ws_size,
                              hipStream_t stream) {
  (void)in_sizes; (void)n_in; (void)out_size; (void)ws_size;
  const float* emb   = (const float*)d_in[0];
  const float* M_in  = (const float*)d_in[1];
  const float* hr0   = (const float*)d_in[2];
  const float* cr0   = (const float*)d_in[3];
  const float* hw0   = (const float*)d_in[4];
  const float* cw0   = (const float*)d_in[5];
  const float* Wih_r = (const float*)d_in[6];
  const float* Whh_r = (const float*)d_in[7];
  const float* bih_r = (const float*)d_in[8];
  const float* bhh_r = (const float*)d_in[9];
  const float* Wih_w = (const float*)d_in[10];
  const float* Whh_w = (const float*)d_in[11];
  const float* bih_w = (const float*)d_in[12];
  const float* bhh_w = (const float*)d_in[13];
  const float* Wc    = (const float*)d_in[14];
  const float* bc    = (const float*)d_in[15];
  float* out = (float*)d_out;

  char* wsb = (char*)d_ws;
  unsigned* flagp = (unsigned*)wsb;          // byte 0
  unsigned* cntp  = (unsigned*)(wsb + 256);  // separate cacheline
  float* wsf = (float*)(wsb + 1024);         // ~15 MB data region

  static int attr_set = -1;
  (void)attr_set;
  hipFuncSetAttribute((const void*)memnet,
                      hipFuncAttributeMaxDynamicSharedMemorySize, LDS_BYTES);

  hipLaunchKernelGGL(memnet, dim3(NBLK), dim3(NTH), LDS_BYTES, stream,
                     emb, M_in, hr0, cr0, hw0, cw0,
                     Wih_r, Whh_r, bih_r, bhh_r,
                     Wih_w, Whh_w, bih_w, bhh_w, Wc, bc,
                     out, flagp, cntp, wsf);
}